// Round 1
// baseline (32799.673 us; speedup 1.0000x reference)
//
#include <hip/hip_runtime.h>
#include <hip/hip_cooperative_groups.h>

namespace cg = cooperative_groups;

#define cB 16
#define cS 512
#define cD 512
#define cL 64
#define cG 16   // blocks per batch

// workspace layout (bytes)
constexpr size_t OFF_F   = 0;                                   // B*S*D f32 (feature rows)
constexpr size_t OFF_U   = OFF_F   + (size_t)cB*cS*cD*4;        // D f32   u = W1a@w2
constexpr size_t OFF_V   = OFF_U   + (size_t)cD*4;              // D f32   v = W1b@w2
constexpr size_t OFF_C0  = OFF_V   + (size_t)cD*4;              // 1 f32   c0 = b1@w2+b2 (padded)
constexpr size_t OFF_SI  = OFF_C0  + 16;                        // B*S f32
constexpr size_t OFF_SJ  = OFF_SI  + (size_t)cB*cS*4;           // B*S f32
constexpr size_t OFF_CLS = OFF_SJ  + (size_t)cB*cS*4;           // B*S i32
constexpr size_t OFF_ADJ = OFF_CLS + (size_t)cB*cS*4;           // B*S*8 u64 adjacency bitmask
constexpr size_t OFF_RM  = OFF_ADJ + (size_t)cB*cS*8*8;         // B*S f32 init rowmax
constexpr size_t OFF_RA  = OFF_RM  + (size_t)cB*cS*4;           // B*S i32 init rowarg
constexpr size_t OFF_CSC = OFF_RA  + (size_t)cB*cS*4;           // B*G f32 candidate score
constexpr size_t OFF_CK  = OFF_CSC + (size_t)cB*cG*4;           // B*G i32 candidate k
constexpr size_t OFF_PSI = OFF_CK  + (size_t)cB*cG*4;           // B*G f32 partial p.u
constexpr size_t OFF_PSJ = OFF_PSI + (size_t)cB*cG*4;           // B*G f32 partial p.v
constexpr size_t OFF_PN  = OFF_PSJ + (size_t)cB*cG*4;           // B*D f32 parent temp

// ---------------- K1: u = W1a@w2, v = W1b@w2, c0 = b1@w2 + b2 ----------------
__global__ void k1_uvc(const float* __restrict__ W1, const float* __restrict__ b1,
                       const float* __restrict__ w2, const float* __restrict__ b2,
                       char* __restrict__ ws) {
    __shared__ float rs[256];
    const int t = threadIdx.x;
    const int r = blockIdx.x;
    float acc;
    if (r < 1024) {
        const float* row = W1 + (size_t)r * cD;
        acc = row[t] * w2[t] + row[t + 256] * w2[t + 256];
    } else {
        acc = b1[t] * w2[t] + b1[t + 256] * w2[t + 256];
    }
    rs[t] = acc; __syncthreads();
    for (int o = 128; o; o >>= 1) { if (t < o) rs[t] += rs[t + o]; __syncthreads(); }
    if (t == 0) {
        if (r < 512)        ((float*)(ws + OFF_U))[r] = rs[0];
        else if (r < 1024)  ((float*)(ws + OFF_V))[r - 512] = rs[0];
        else                ((float*)(ws + OFF_C0))[0] = rs[0] + b2[0];
    }
}

// ---------------- K2: gather feats, si = f@u, sj = f@v ----------------
__global__ void k2_feat(const int* __restrict__ tok, const float* __restrict__ emb,
                        char* __restrict__ ws) {
    __shared__ float ru[256], rv[256];
    const int t = threadIdx.x;
    const int bs = blockIdx.x;            // b*S + s
    const float* U = (const float*)(ws + OFF_U);
    const float* V = (const float*)(ws + OFF_V);
    float* F = (float*)(ws + OFF_F);
    const int tk = tok[bs];
    const float* src = emb + (size_t)tk * cD;
    float* dst = F + (size_t)bs * cD;
    const float e0 = src[t], e1 = src[t + 256];
    dst[t] = e0; dst[t + 256] = e1;
    ru[t] = e0 * U[t] + e1 * U[t + 256];
    rv[t] = e0 * V[t] + e1 * V[t + 256];
    __syncthreads();
    for (int o = 128; o; o >>= 1) {
        if (t < o) { ru[t] += ru[t + o]; rv[t] += rv[t + o]; }
        __syncthreads();
    }
    if (t == 0) {
        ((float*)(ws + OFF_SI))[bs] = ru[0];
        ((float*)(ws + OFF_SJ))[bs] = rv[0];
    }
}

// ---------------- K3: logits = f@pos_W + pos_b ; cls = argmax (first max) ----------------
__global__ void k3_cls(const float* __restrict__ posW, const float* __restrict__ posb,
                       char* __restrict__ ws) {
    const int t = threadIdx.x;            // 0..63, one wave
    const int bs = blockIdx.x;
    const float* frow = (const float*)(ws + OFF_F) + (size_t)bs * cD;
    float acc = posb[t];
    for (int k = 0; k < cD; k++) acc += frow[k] * posW[(size_t)k * cL + t];
    int idx = t;
    for (int off = 32; off; off >>= 1) {
        float ov = __shfl_down(acc, off, 64);
        int   oi = __shfl_down(idx, off, 64);
        if (ov > acc || (ov == acc && oi < idx)) { acc = ov; idx = oi; }
    }
    if (t == 0) ((int*)(ws + OFF_CLS))[bs] = idx;
}

// ---------------- K4: adjacency bitmask + initial per-row max ----------------
__global__ void k4_adj(char* __restrict__ ws) {
    __shared__ float rsv[256]; __shared__ int rsk[256];
    const int t = threadIdx.x;
    const int bs = blockIdx.x;
    const int b = bs >> 9, r = bs & 511;
    const int* cls = (const int*)(ws + OFF_CLS) + (size_t)b * cS;
    const float* SJ = (const float*)(ws + OFF_SJ) + (size_t)b * cS;
    const float sir = ((const float*)(ws + OFF_SI))[bs];
    const float c0 = *(const float*)(ws + OFF_C0);
    unsigned long long* adjrow = (unsigned long long*)(ws + OFF_ADJ) + (size_t)bs * 8;
    const int cr = cls[r];
    float bv = -INFINITY; int bc = 0;
    for (int p = 0; p < 2; p++) {
        const int c = p * 256 + t;
        int dd = c - r; if (dd < 0) dd = -dd;
        const bool allowed = (c != r) && (dd == 1 || cls[c] == cr);
        unsigned long long m = __ballot(allowed);
        if ((t & 63) == 0) adjrow[p * 4 + (t >> 6)] = m;
        if (allowed) {
            float val = sir + SJ[c] + c0;
            if (val > bv || (val == bv && c < bc)) { bv = val; bc = c; }
        }
    }
    rsv[t] = bv; rsk[t] = bc; __syncthreads();
    for (int o = 128; o; o >>= 1) {
        if (t < o) {
            float s2 = rsv[t + o]; int k2 = rsk[t + o];
            if (s2 > rsv[t] || (s2 == rsv[t] && k2 < rsk[t])) { rsv[t] = s2; rsk[t] = k2; }
        }
        __syncthreads();
    }
    if (t == 0) { ((float*)(ws + OFF_RM))[bs] = rsv[0]; ((int*)(ws + OFF_RA))[bs] = rsk[0]; }
}

// ---------------- K5: cooperative sequential parser ----------------
// grid = 256 blocks: b = blockIdx&15 (XCD-local grouping), g = blockIdx>>4.
// Each block owns 32 rows (argmax) + 32 output dims (matvec, W1 slice in VGPRs).
__global__ void __launch_bounds__(256, 1)
parse_main(const float* __restrict__ W1, const float* __restrict__ b1,
           char* __restrict__ ws, float* __restrict__ out) {
    cg::grid_group grid = cg::this_grid();
    const int t = threadIdx.x;
    const int b = blockIdx.x & 15;
    const int g = blockIdx.x >> 4;
    const int r0 = g * 32;
    const int d0 = g * 32;

    float* F  = (float*)(ws + OFF_F) + (size_t)b * cS * cD;
    float* SI = (float*)(ws + OFF_SI) + (size_t)b * cS;
    float* SJ = (float*)(ws + OFF_SJ) + (size_t)b * cS;
    unsigned long long* ADJb = (unsigned long long*)(ws + OFF_ADJ) + (size_t)b * cS * 8;
    float* RM = (float*)(ws + OFF_RM) + (size_t)b * cS;
    int*   RA = (int*)(ws + OFF_RA) + (size_t)b * cS;
    float* CSc = (float*)(ws + OFF_CSC) + (size_t)b * cG;
    int*   CK  = (int*)(ws + OFF_CK)  + (size_t)b * cG;
    float* PSI = (float*)(ws + OFF_PSI) + (size_t)b * cG;
    float* PSJ = (float*)(ws + OFF_PSJ) + (size_t)b * cG;
    float* PN  = (float*)(ws + OFF_PN)  + (size_t)b * cD;
    const float* U = (const float*)(ws + OFF_U);
    const float* V = (const float*)(ws + OFF_V);
    const float c0 = *(const float*)(ws + OFF_C0);

    __shared__ float xls[1024];
    __shared__ float rsh[256];
    __shared__ int   rk[256];
    __shared__ float rv2[32];
    __shared__ float s_best; __shared__ int s_bi, s_bj;
    __shared__ float s_sin, s_sjn;
    __shared__ int rescanList[34]; __shared__ int nresc;
    __shared__ float rmax[32]; __shared__ int rarg[32];
    __shared__ int s_prev_i; __shared__ float s_prev_si, s_prev_sj;

    // W1 slice into registers: thread (ks,od) holds W1[ks*128 .. +127][d0+od]
    const int ks = t >> 5, od = t & 31, d = d0 + od, kbase = ks * 128;
    float w[128];
#pragma unroll
    for (int kk = 0; kk < 128; kk++) w[kk] = W1[(size_t)(kbase + kk) * cD + d];

    bool myAlive = true;
    if (t < 32) { rmax[t] = RM[r0 + t]; rarg[t] = RA[r0 + t]; }
    if (t == 0) s_prev_i = -1;
    float tot = 0.0f;
    __syncthreads();

    for (int it = 0; it < cS - 1; ++it) {
        // ---- A: block-local argmax over own rows ----
        if (t < 32) { rsh[t] = rmax[t]; rk[t] = (r0 + t) * cS + rarg[t]; }
        __syncthreads();
        if (t == 0) {
            float bsv = rsh[0]; int bk = rk[0];
            for (int q = 1; q < 32; q++) {
                float s = rsh[q]; int k = rk[q];
                if (s > bsv || (s == bsv && k < bk)) { bsv = s; bk = k; }
            }
            CSc[g] = bsv; CK[g] = bk;
        }
        grid.sync();   // s1

        // ---- B': every block derives global best; leader does side effects ----
        if (t == 0) {
            float bsv = -INFINITY; int bk = 0x7fffffff;
            for (int q = 0; q < cG; q++) {
                float s = CSc[q]; int k = CK[q];
                if (s > bsv || (s == bsv && k < bk)) { bsv = s; bk = k; }
            }
            s_best = bsv; s_bi = bk >> 9; s_bj = bk & (cS - 1);
            if (g == 0) {
                tot += bsv;
                out[16 + b * (2 * (cS - 1)) + it * 2 + 0] = (float)(bk >> 9);
                out[16 + b * (2 * (cS - 1)) + it * 2 + 1] = (float)(bk & (cS - 1));
                // commit previous step's si/sj[i] (no reader races: rescans happen after s2)
                if (s_prev_i >= 0) { SI[s_prev_i] = s_prev_si; SJ[s_prev_i] = s_prev_sj; }
            }
        }
        __syncthreads();
        const int bi = s_bi, bj = s_bj;

        // ---- C: parent matvec (W1 slice in regs), partial p.u / p.v ----
        {
            const float* fi = F + (size_t)bi * cD;
            const float* fj = F + (size_t)bj * cD;
            xls[t] = fi[t]; xls[256 + t] = fi[256 + t];
            xls[512 + t] = fj[t]; xls[768 + t] = fj[256 + t];
            __syncthreads();
            float acc = 0.f;
#pragma unroll
            for (int kk = 0; kk < 128; kk++) acc += w[kk] * xls[kbase + kk];
            rsh[t] = acc;
            __syncthreads();
            if (t < 32) {
                float p = 0.f;
#pragma unroll
                for (int q = 0; q < 8; q++) p += rsh[q * 32 + t];
                p += b1[d0 + t];
                PN[d0 + t] = p;
                rv2[t] = p * U[d0 + t];
                rsh[t] = p * V[d0 + t];
            }
            __syncthreads();
            if (t == 0) {
                float su = 0.f, sv = 0.f;
                for (int q = 0; q < 32; q++) { su += rv2[q]; sv += rsh[q]; }
                PSI[g] = su; PSJ[g] = sv;
            }
        }
        grid.sync();   // s2

        // ---- D: commit parent, update adjacency + incremental rowmax ----
        if (t == 0) {
            float su = 0.f, sv = 0.f;
            for (int q = 0; q < cG; q++) { su += PSI[q]; sv += PSJ[q]; }
            s_sin = su; s_sjn = sv;
            s_prev_i = bi; s_prev_si = su; s_prev_sj = sv;
            nresc = 0;
        }
        __syncthreads();
        const float sin_ = s_sin, sjn_ = s_sjn;
        if (t < 32) F[(size_t)bi * cD + d0 + t] = PN[d0 + t];   // safe: all staging done pre-s2

        const int wbi = bi >> 6, wbj = bj >> 6;
        const unsigned long long mbi = 1ull << (bi & 63), mbj = 1ull << (bj & 63);
        if (t < 32) {
            const int r = r0 + t;
            if (r == bj) {
                if (myAlive) { myAlive = false; rmax[t] = -INFINITY; }
            } else if (myAlive && r != bi) {
                unsigned long long* row = ADJb + (size_t)r * 8;
                unsigned long long wi = row[wbi];
                unsigned long long wj = (wbj == wbi) ? wi : row[wbj];
                const bool nb = ((wi & mbi) != 0ull) || ((wj & mbj) != 0ull);
                if (wbi == wbj) {
                    row[wbi] = (wi & ~(mbi | mbj)) | (nb ? mbi : 0ull);
                } else {
                    row[wbi] = (wi & ~mbi) | (nb ? mbi : 0ull);
                    row[wbj] = wj & ~mbj;
                }
                const int ra = rarg[t];
                if (ra == bi || ra == bj) {
                    int slot = atomicAdd(&nresc, 1); rescanList[slot] = r;
                } else if (nb) {
                    const float val = SI[r] + sjn_ + c0;
                    if (val > rmax[t] || (val == rmax[t] && bi < ra)) { rmax[t] = val; rarg[t] = bi; }
                }
            }
        }
        if ((bi >> 5) == g) {   // row bi owned here: rebuild row = old_i | old_j minus {i,j}
            if (t >= 32 && t < 40) {
                const int wq = t - 32;
                unsigned long long nw = ADJb[(size_t)bi * 8 + wq] | ADJb[(size_t)bj * 8 + wq];
                if (wq == wbi) nw &= ~mbi;
                if (wq == wbj) nw &= ~mbj;
                ADJb[(size_t)bi * 8 + wq] = nw;
            }
            if (t == 32) { int slot = atomicAdd(&nresc, 1); rescanList[slot] = bi; }
        }
        __syncthreads();
        const int nr = nresc;
        for (int q = 0; q < nr; q++) {
            const int r = rescanList[q];
            const float sir = (r == bi) ? sin_ : SI[r];
            const unsigned long long* row = ADJb + (size_t)r * 8;
            float bv = -INFINITY; int bc = 0;
#pragma unroll
            for (int p = 0; p < 2; p++) {
                const int c = p * 256 + t;
                const unsigned long long wq = row[c >> 6];
                if ((wq >> (c & 63)) & 1ull) {
                    const float sjc = (c == bi) ? sjn_ : SJ[c];
                    const float val = sir + sjc + c0;
                    if (val > bv || (val == bv && c < bc)) { bv = val; bc = c; }
                }
            }
            rsh[t] = bv; rk[t] = bc;
            __syncthreads();
            for (int o = 128; o; o >>= 1) {
                if (t < o) {
                    float s2 = rsh[t + o]; int k2 = rk[t + o];
                    if (s2 > rsh[t] || (s2 == rsh[t] && k2 < rk[t])) { rsh[t] = s2; rk[t] = k2; }
                }
                __syncthreads();
            }
            if (t == 0) { rmax[r - r0] = rsh[0]; rarg[r - r0] = rk[0]; }
            __syncthreads();
        }
        // next A only reads block-local rmax/rarg -> no extra grid sync needed
    }
    if (g == 0 && t == 0) out[b] = tot;
}

extern "C" void kernel_launch(void* const* d_in, const int* in_sizes, int n_in,
                              void* d_out, int out_size, void* d_ws, size_t ws_size,
                              hipStream_t stream) {
    const int*   token_ids = (const int*)d_in[0];
    const float* vocab_emb = (const float*)d_in[1];
    const float* pos_W     = (const float*)d_in[2];
    const float* pos_b     = (const float*)d_in[3];
    const float* W1        = (const float*)d_in[4];
    const float* b1        = (const float*)d_in[5];
    const float* w2        = (const float*)d_in[6];
    const float* b2        = (const float*)d_in[7];
    float* out = (float*)d_out;
    char*  ws  = (char*)d_ws;

    k1_uvc<<<1025, 256, 0, stream>>>(W1, b1, w2, b2, ws);
    k2_feat<<<cB * cS, 256, 0, stream>>>(token_ids, vocab_emb, ws);
    k3_cls<<<cB * cS, 64, 0, stream>>>(pos_W, pos_b, ws);
    k4_adj<<<cB * cS, 256, 0, stream>>>(ws);

    void* args[] = { (void*)&W1, (void*)&b1, (void*)&ws, (void*)&out };
    hipLaunchCooperativeKernel((void*)parse_main, dim3(cB * cG), dim3(256),
                               args, 0, stream);
}

// Round 2
// 10577.884 us; speedup vs baseline: 3.1008x; 3.1008x over previous
//
#include <hip/hip_runtime.h>

#define cB 16
#define cS 512
#define cD 512
#define cL 64
#define cG 8     // blocks per batch
#define cT 512   // threads per block
#define cR 64    // rows / output-dims per block

// workspace layout (bytes)
constexpr size_t OFF_F   = 0;                                   // B*S*D f32
constexpr size_t OFF_U   = OFF_F   + (size_t)cB*cS*cD*4;        // D f32
constexpr size_t OFF_V   = OFF_U   + (size_t)cD*4;              // D f32
constexpr size_t OFF_C0  = OFF_V   + (size_t)cD*4;              // 1 f32 (padded 64B)
constexpr size_t OFF_SI  = OFF_C0  + 64;                        // B*S f32
constexpr size_t OFF_SJ  = OFF_SI  + (size_t)cB*cS*4;           // B*S f32
constexpr size_t OFF_CLS = OFF_SJ  + (size_t)cB*cS*4;           // B*S i32
constexpr size_t OFF_ADJ = OFF_CLS + (size_t)cB*cS*4;           // B*S*8 u64
constexpr size_t OFF_RM  = OFF_ADJ + (size_t)cB*cS*8*8;         // B*S f32
constexpr size_t OFF_RA  = OFF_RM  + (size_t)cB*cS*4;           // B*S i32
constexpr size_t OFF_CSC = OFF_RA  + (size_t)cB*cS*4;           // B*G f32
constexpr size_t OFF_CK  = OFF_CSC + (size_t)cB*cG*4;           // B*G i32
constexpr size_t OFF_PSI = OFF_CK  + (size_t)cB*cG*4;           // B*G f32
constexpr size_t OFF_PSJ = OFF_PSI + (size_t)cB*cG*4;           // B*G f32
constexpr size_t OFF_BAR = ((OFF_PSJ + (size_t)cB*cG*4 + 127) & ~(size_t)127); // B*128B

// ---- per-batch 8-block sense-reversing barrier (agent scope acq/rel) ----
__device__ __forceinline__ void batch_bar(unsigned* bar, int t) {
    __syncthreads();
    if (t == 0) {
        unsigned g = __hip_atomic_load(bar + 1, __ATOMIC_RELAXED, __HIP_MEMORY_SCOPE_AGENT);
        unsigned a = __hip_atomic_fetch_add(bar, 1u, __ATOMIC_ACQ_REL, __HIP_MEMORY_SCOPE_AGENT);
        if (a == cG - 1) {
            __hip_atomic_store(bar, 0u, __ATOMIC_RELAXED, __HIP_MEMORY_SCOPE_AGENT);
            __hip_atomic_store(bar + 1, g + 1u, __ATOMIC_RELEASE, __HIP_MEMORY_SCOPE_AGENT);
        } else {
            while (__hip_atomic_load(bar + 1, __ATOMIC_ACQUIRE, __HIP_MEMORY_SCOPE_AGENT) == g)
                __builtin_amdgcn_s_sleep(1);
        }
    }
    __syncthreads();
}

// ---------------- K1: u = W1a@w2, v = W1b@w2, c0 = b1@w2 + b2 (+barrier init) --------
__global__ void k1_uvc(const float* __restrict__ W1, const float* __restrict__ b1,
                       const float* __restrict__ w2, const float* __restrict__ b2,
                       char* __restrict__ ws) {
    const int t = threadIdx.x;
    const int r = blockIdx.x;
    if (r == 1025) {   // zero barrier state (ws is poisoned 0xAA before every launch)
        unsigned* bar = (unsigned*)(ws + OFF_BAR);
        bar[t] = 0u; bar[t + 256] = 0u;
        return;
    }
    __shared__ float rs[256];
    float acc;
    if (r < 1024) {
        const float* row = W1 + (size_t)r * cD;
        acc = row[t] * w2[t] + row[t + 256] * w2[t + 256];
    } else {
        acc = b1[t] * w2[t] + b1[t + 256] * w2[t + 256];
    }
    rs[t] = acc; __syncthreads();
    for (int o = 128; o; o >>= 1) { if (t < o) rs[t] += rs[t + o]; __syncthreads(); }
    if (t == 0) {
        if (r < 512)        ((float*)(ws + OFF_U))[r] = rs[0];
        else if (r < 1024)  ((float*)(ws + OFF_V))[r - 512] = rs[0];
        else                ((float*)(ws + OFF_C0))[0] = rs[0] + b2[0];
    }
}

// ---------------- K2: gather feats, si = f@u, sj = f@v ----------------
__global__ void k2_feat(const int* __restrict__ tok, const float* __restrict__ emb,
                        char* __restrict__ ws) {
    __shared__ float ru[256], rv[256];
    const int t = threadIdx.x;
    const int bs = blockIdx.x;
    const float* U = (const float*)(ws + OFF_U);
    const float* V = (const float*)(ws + OFF_V);
    float* F = (float*)(ws + OFF_F);
    const int tk = tok[bs];
    const float* src = emb + (size_t)tk * cD;
    float* dst = F + (size_t)bs * cD;
    const float e0 = src[t], e1 = src[t + 256];
    dst[t] = e0; dst[t + 256] = e1;
    ru[t] = e0 * U[t] + e1 * U[t + 256];
    rv[t] = e0 * V[t] + e1 * V[t + 256];
    __syncthreads();
    for (int o = 128; o; o >>= 1) {
        if (t < o) { ru[t] += ru[t + o]; rv[t] += rv[t + o]; }
        __syncthreads();
    }
    if (t == 0) {
        ((float*)(ws + OFF_SI))[bs] = ru[0];
        ((float*)(ws + OFF_SJ))[bs] = rv[0];
    }
}

// ---------------- K3: logits argmax -> cls ----------------
__global__ void k3_cls(const float* __restrict__ posW, const float* __restrict__ posb,
                       char* __restrict__ ws) {
    const int t = threadIdx.x;            // one wave
    const int bs = blockIdx.x;
    const float* frow = (const float*)(ws + OFF_F) + (size_t)bs * cD;
    float acc = posb[t];
    for (int k = 0; k < cD; k++) acc += frow[k] * posW[(size_t)k * cL + t];
    int idx = t;
    for (int off = 32; off; off >>= 1) {
        float ov = __shfl_down(acc, off, 64);
        int   oi = __shfl_down(idx, off, 64);
        if (ov > acc || (ov == acc && oi < idx)) { acc = ov; idx = oi; }
    }
    if (t == 0) ((int*)(ws + OFF_CLS))[bs] = idx;
}

// ---------------- K4: adjacency bitmask + initial per-row max ----------------
__global__ void k4_adj(char* __restrict__ ws) {
    __shared__ float rsv[256]; __shared__ int rsk[256];
    const int t = threadIdx.x;
    const int bs = blockIdx.x;
    const int b = bs >> 9, r = bs & 511;
    const int* cls = (const int*)(ws + OFF_CLS) + (size_t)b * cS;
    const float* SJ = (const float*)(ws + OFF_SJ) + (size_t)b * cS;
    const float sir = ((const float*)(ws + OFF_SI))[bs];
    const float c0 = *(const float*)(ws + OFF_C0);
    unsigned long long* adjrow = (unsigned long long*)(ws + OFF_ADJ) + (size_t)bs * 8;
    const int cr = cls[r];
    float bv = -INFINITY; int bc = 0;
    for (int p = 0; p < 2; p++) {
        const int c = p * 256 + t;
        int dd = c - r; if (dd < 0) dd = -dd;
        const bool allowed = (c != r) && (dd == 1 || cls[c] == cr);
        unsigned long long m = __ballot(allowed);
        if ((t & 63) == 0) adjrow[p * 4 + (t >> 6)] = m;
        if (allowed) {
            float val = sir + SJ[c] + c0;
            if (val > bv || (val == bv && c < bc)) { bv = val; bc = c; }
        }
    }
    rsv[t] = bv; rsk[t] = bc; __syncthreads();
    for (int o = 128; o; o >>= 1) {
        if (t < o) {
            float s2 = rsv[t + o]; int k2 = rsk[t + o];
            if (s2 > rsv[t] || (s2 == rsv[t] && k2 < rsk[t])) { rsv[t] = s2; rsk[t] = k2; }
        }
        __syncthreads();
    }
    if (t == 0) { ((float*)(ws + OFF_RM))[bs] = rsv[0]; ((int*)(ws + OFF_RA))[bs] = rsk[0]; }
}

// ---------------- K5: parser — 8 blocks x 512 threads per batch ----------------
__global__ void __launch_bounds__(cT, 2)
parse_main(const float* __restrict__ W1, const float* __restrict__ b1,
           char* __restrict__ ws, float* __restrict__ out) {
    const int t = threadIdx.x;
    const int b = blockIdx.x & 15;        // batch; members share blockIdx%8 -> same XCD
    const int g = blockIdx.x >> 4;        // 0..7
    const int r0 = g * cR, d0 = g * cR;

    float* F  = (float*)(ws + OFF_F) + (size_t)b * cS * cD;
    float* SI = (float*)(ws + OFF_SI) + (size_t)b * cS;
    float* SJ = (float*)(ws + OFF_SJ) + (size_t)b * cS;
    unsigned long long* ADJb = (unsigned long long*)(ws + OFF_ADJ) + (size_t)b * cS * 8;
    const float* RM = (const float*)(ws + OFF_RM) + (size_t)b * cS;
    const int*   RA = (const int*)(ws + OFF_RA) + (size_t)b * cS;
    float* CSc = (float*)(ws + OFF_CSC) + (size_t)b * cG;
    int*   CK  = (int*)(ws + OFF_CK)  + (size_t)b * cG;
    float* PSI = (float*)(ws + OFF_PSI) + (size_t)b * cG;
    float* PSJ = (float*)(ws + OFF_PSJ) + (size_t)b * cG;
    unsigned* bar = (unsigned*)(ws + OFF_BAR) + (size_t)b * 32;   // 128B stride
    const float* U = (const float*)(ws + OFF_U);
    const float* V = (const float*)(ws + OFF_V);
    const float c0 = *(const float*)(ws + OFF_C0);

    __shared__ float xls[1024];
    __shared__ float rsh[cT];
    __shared__ int   rk[cT];
    __shared__ float pn[cR];
    __shared__ float rmax[cR]; __shared__ int rarg[cR];
    __shared__ int s_bi, s_bj;
    __shared__ float s_sin, s_sjn;
    __shared__ int rescanList[cR + 2]; __shared__ int nresc;
    __shared__ int s_prev_i; __shared__ float s_prev_si, s_prev_sj;

    // W1 slice: thread (ks,od) holds W1[ks*128 .. +127][d0+od]  (128 VGPRs)
    const int ks = t >> 6, od = t & 63, kbase = ks * 128;
    float w[128];
#pragma unroll
    for (int kk = 0; kk < 128; kk++) w[kk] = W1[(size_t)(kbase + kk) * cD + (d0 + od)];

    float uv = 0.f, vv = 0.f, b1v = 0.f;
    bool myAlive = true;
    if (t < cR) {
        rmax[t] = RM[r0 + t]; rarg[t] = RA[r0 + t];
        uv = U[d0 + t]; vv = V[d0 + t]; b1v = b1[d0 + t];
    }
    if (t == 0) s_prev_i = -1;
    float tot = 0.f;
    __syncthreads();

    for (int it = 0; it < cS - 1; ++it) {
        // ---- A: block-local argmax over own 64 rows (wave 0) ----
        if (t < cR) {
            float av = rmax[t]; int ak = (r0 + t) * cS + rarg[t];
            for (int off = 32; off; off >>= 1) {
                float ov = __shfl_down(av, off, 64);
                int   ok = __shfl_down(ak, off, 64);
                if (ov > av || (ov == av && ok < ak)) { av = ov; ak = ok; }
            }
            if (t == 0) { CSc[g] = av; CK[g] = ak; }
        }
        batch_bar(bar, t);   // s1

        // ---- B: global (i,j); leader side effects ----
        if (t < 64) {
            float bv; int bk;
            if (t < cG) { bv = CSc[t]; bk = CK[t]; }
            else        { bv = -INFINITY; bk = 0x7fffffff; }
            for (int off = cG / 2; off; off >>= 1) {
                float ov = __shfl_down(bv, off, 64);
                int   ok = __shfl_down(bk, off, 64);
                if (ov > bv || (ov == bv && ok < bk)) { bv = ov; bk = ok; }
            }
            if (t == 0) {
                s_bi = bk >> 9; s_bj = bk & (cS - 1);
                if (g == 0) {
                    tot += bv;
                    out[16 + b * (2 * (cS - 1)) + it * 2 + 0] = (float)(bk >> 9);
                    out[16 + b * (2 * (cS - 1)) + it * 2 + 1] = (float)(bk & (cS - 1));
                    // commit previous step's si/sj[i]; readers only touch these after s2
                    if (s_prev_i >= 0) { SI[s_prev_i] = s_prev_si; SJ[s_prev_i] = s_prev_sj; }
                }
            }
        }
        __syncthreads();
        const int bi = s_bi, bj = s_bj;

        // ---- C: parent matvec (W1 in regs) + p.u / p.v partials ----
        {
            const float* fi = F + (size_t)bi * cD;
            const float* fj = F + (size_t)bj * cD;
            xls[t] = fi[t]; xls[512 + t] = fj[t];
            __syncthreads();
            float acc = 0.f;
#pragma unroll
            for (int kk = 0; kk < 128; kk++) acc += w[kk] * xls[kbase + kk];
            rsh[t] = acc;
            __syncthreads();
            if (t < cR) {
                float p = 0.f;
#pragma unroll
                for (int q = 0; q < 8; q++) p += rsh[q * 64 + t];
                p += b1v;
                pn[t] = p;
                float pu = p * uv, pv = p * vv;
                for (int off = 32; off; off >>= 1) {
                    pu += __shfl_down(pu, off, 64);
                    pv += __shfl_down(pv, off, 64);
                }
                if (t == 0) { PSI[g] = pu; PSJ[g] = pv; }
            }
        }
        batch_bar(bar, t);   // s2

        // ---- D: commit parent, adjacency + incremental rowmax, rescans ----
        if (t < 64) {
            float su, sv;
            if (t < cG) { su = PSI[t]; sv = PSJ[t]; } else { su = 0.f; sv = 0.f; }
            for (int off = cG / 2; off; off >>= 1) {
                su += __shfl_down(su, off, 64);
                sv += __shfl_down(sv, off, 64);
            }
            if (t == 0) {
                s_sin = su; s_sjn = sv;
                s_prev_i = bi; s_prev_si = su; s_prev_sj = sv;
                nresc = 0;
            }
        }
        __syncthreads();
        const float sin_ = s_sin, sjn_ = s_sjn;
        const float sjc_t = (t == bi) ? sjn_ : SJ[t];   // this step's column score, c = t
        if (t < cR) F[(size_t)bi * cD + d0 + t] = pn[t];

        const int wbi = bi >> 6, wbj = bj >> 6;
        const unsigned long long mbi = 1ull << (bi & 63), mbj = 1ull << (bj & 63);
        if (t < cR) {
            const int r = r0 + t;
            if (r == bj) {
                if (myAlive) { myAlive = false; rmax[t] = -INFINITY; }
            } else if (myAlive && r != bi) {
                unsigned long long* row = ADJb + (size_t)r * 8;
                unsigned long long wi = row[wbi];
                unsigned long long wj = (wbj == wbi) ? wi : row[wbj];
                const bool nb = ((wi & mbi) != 0ull) || ((wj & mbj) != 0ull);
                if (wbi == wbj) {
                    row[wbi] = (wi & ~(mbi | mbj)) | (nb ? mbi : 0ull);
                } else {
                    row[wbi] = (wi & ~mbi) | (nb ? mbi : 0ull);
                    row[wbj] = wj & ~mbj;
                }
                const int ra = rarg[t];
                if (ra == bi || ra == bj) {
                    int slot = atomicAdd(&nresc, 1); rescanList[slot] = r;
                } else if (nb) {
                    const float val = SI[r] + sjn_ + c0;
                    if (val > rmax[t] || (val == rmax[t] && bi < ra)) { rmax[t] = val; rarg[t] = bi; }
                }
            }
        } else if ((bi >> 6) == g && t >= 64 && t < 72) {
            // row bi owned here: rebuild = (row_i | row_j) minus {bi, bj}
            const int wq = t - 64;
            unsigned long long nw = ADJb[(size_t)bi * 8 + wq] | ADJb[(size_t)bj * 8 + wq];
            if (wq == wbi) nw &= ~mbi;
            if (wq == wbj) nw &= ~mbj;
            ADJb[(size_t)bi * 8 + wq] = nw;
            if (wq == 0) { int slot = atomicAdd(&nresc, 1); rescanList[slot] = bi; }
        }
        __syncthreads();
        const int nr = nresc;
        for (int q = 0; q < nr; q++) {
            const int r = rescanList[q];
            const float sir = (r == bi) ? sin_ : SI[r];
            const unsigned long long word = ADJb[(size_t)r * 8 + (t >> 6)];
            float bv = ((word >> (t & 63)) & 1ull) ? (sir + sjc_t + c0) : -INFINITY;
            int bc = t;
            for (int off = 32; off; off >>= 1) {
                float ov = __shfl_down(bv, off, 64);
                int   ok = __shfl_down(bc, off, 64);
                if (ov > bv || (ov == bv && ok < bc)) { bv = ov; bc = ok; }
            }
            if ((t & 63) == 0) { rsh[t >> 6] = bv; rk[t >> 6] = bc; }
            __syncthreads();
            if (t < 64) {
                if (t < 8) { bv = rsh[t]; bc = rk[t]; }
                else       { bv = -INFINITY; bc = 0x7fffffff; }
                for (int off = 4; off; off >>= 1) {
                    float ov = __shfl_down(bv, off, 64);
                    int   ok = __shfl_down(bc, off, 64);
                    if (ov > bv || (ov == bv && ok < bc)) { bv = ov; bc = ok; }
                }
                if (t == 0) { rmax[r - r0] = bv; rarg[r - r0] = bc; }
            }
            __syncthreads();
        }
    }
    if (g == 0 && t == 0) out[b] = tot;
}

extern "C" void kernel_launch(void* const* d_in, const int* in_sizes, int n_in,
                              void* d_out, int out_size, void* d_ws, size_t ws_size,
                              hipStream_t stream) {
    const int*   token_ids = (const int*)d_in[0];
    const float* vocab_emb = (const float*)d_in[1];
    const float* pos_W     = (const float*)d_in[2];
    const float* pos_b     = (const float*)d_in[3];
    const float* W1        = (const float*)d_in[4];
    const float* b1        = (const float*)d_in[5];
    const float* w2        = (const float*)d_in[6];
    const float* b2        = (const float*)d_in[7];
    float* out = (float*)d_out;
    char*  ws  = (char*)d_ws;

    k1_uvc<<<1026, 256, 0, stream>>>(W1, b1, w2, b2, ws);
    k2_feat<<<cB * cS, 256, 0, stream>>>(token_ids, vocab_emb, ws);
    k3_cls<<<cB * cS, 64, 0, stream>>>(pos_W, pos_b, ws);
    k4_adj<<<cB * cS, 256, 0, stream>>>(ws);

    // cooperative launch only for the co-residency guarantee (custom barriers inside)
    void* args[] = { (void*)&W1, (void*)&b1, (void*)&ws, (void*)&out };
    hipLaunchCooperativeKernel((void*)parse_main, dim3(cB * cG), dim3(cT),
                               args, 0, stream);
}